// Round 7
// baseline (521.977 us; speedup 1.0000x reference)
//
#include <hip/hip_runtime.h>
#include <hip/hip_cooperative_groups.h>
#include <math.h>

namespace cg = cooperative_groups;

#define WAVE 64
#define KMAX 32   // per-node edge-bucket capacity; P(deg>=32 | Poisson(4)) ~ 1e-18

typedef __attribute__((ext_vector_type(8))) short bf16x8;
typedef __attribute__((ext_vector_type(4))) float f32x4;

// bf16 <-> f32 helpers (bit-level, RNE on pack)
__device__ __forceinline__ unsigned short f2b(float f) {
    unsigned u = __float_as_uint(f);
    unsigned r = (u + 0x7FFFu + ((u >> 16) & 1u)) >> 16;
    return (unsigned short)r;
}
__device__ __forceinline__ float b2f(unsigned short u) {
    return __uint_as_float(((unsigned)u) << 16);
}
__device__ __forceinline__ float frcp(float x)   { return __builtin_amdgcn_rcpf(x); }
__device__ __forceinline__ float frsq(float x)   { return __builtin_amdgcn_rsqf(x); }
__device__ __forceinline__ float fsqrt2(float x) { return __builtin_amdgcn_sqrtf(x); }
__device__ __forceinline__ float silu(float x)   { return x * frcp(1.f + __expf(-x)); }
__device__ __forceinline__ float facosh(float x) { return __logf(x + fsqrt2(x * x - 1.f)); }

struct KP {
    const float* x_hyp; const int* ei; const int* et; const float* ew;
    const float* lin_w; const float* lin_b; const float* ln_g; const float* ln_b;
    const float* emb; const float* w1; const float* b1; const float* w2; const float* b2;
    const float* sib; const float* curv;
    float* out;
    float* xtf; unsigned short* xtan_bf;
    unsigned short* xlin0; unsigned short* acat0; unsigned short* xlin1; unsigned short* acat1;
    int2* epack; unsigned short* lw_bf; unsigned short* Wt_bf; float* ae; int* deg;
    int E, N, L, ECH, NT, PB, ZB;
};

// ---------------------------------------------------------------------------
// Dual GEMM for ONE 16-node tile staged in LDS (sm[16*136], bf16 rows).
// 4 waves split 8 column tiles (2 per wave). 3 internal barriers.
// ---------------------------------------------------------------------------
__device__ __forceinline__ void dual_gemm_16(
    unsigned short* sm,
    const unsigned short* __restrict__ LW, const unsigned short* __restrict__ WT,
    const float* __restrict__ bias,
    unsigned short* __restrict__ xlin, unsigned short* __restrict__ acat,
    int base, int N, int tid)
{
    int wave = tid >> 6;
    int lane = tid & 63;
    int quad = lane >> 4;
    int l16  = lane & 15;
    int nloc = tid >> 4;

    __syncthreads();                       // sm rows fully staged by callers

    bf16x8 a[4];
    #pragma unroll
    for (int kk = 0; kk < 4; ++kk)
        a[kk] = *(const bf16x8*)&sm[l16 * 136 + kk * 32 + quad * 8];

    f32x4 acc[2];
    acc[0] = (f32x4){0.f, 0.f, 0.f, 0.f};
    acc[1] = (f32x4){0.f, 0.f, 0.f, 0.f};
    #pragma unroll
    for (int kk = 0; kk < 4; ++kk) {
        #pragma unroll
        for (int t = 0; t < 2; ++t) {
            int nt = wave * 2 + t;
            bf16x8 b = *(const bf16x8*)&LW[(size_t)(nt * 16 + l16) * 128 + kk * 32 + quad * 8];
            acc[t] = __builtin_amdgcn_mfma_f32_16x16x32_bf16(a[kk], b, acc[t], 0, 0, 0);
        }
    }
    __syncthreads();                       // everyone done reading sm input
    #pragma unroll
    for (int t = 0; t < 2; ++t) {
        int nt = wave * 2 + t;
        float bv = bias[nt * 16 + l16];
        #pragma unroll
        for (int r = 0; r < 4; ++r)
            sm[(quad * 4 + r) * 136 + nt * 16 + l16] = f2b(acc[t][r] + bv);
    }
    __syncthreads();                       // GEMM1 result staged

    bf16x8 a2[4];
    #pragma unroll
    for (int kk = 0; kk < 4; ++kk)
        a2[kk] = *(const bf16x8*)&sm[l16 * 136 + kk * 32 + quad * 8];
    int node = base + nloc;
    if (node < N)
        *(bf16x8*)&xlin[(size_t)node * 128 + 8 * l16] =
            *(const bf16x8*)&sm[nloc * 136 + 8 * l16];

    f32x4 acc2[2];
    acc2[0] = (f32x4){0.f, 0.f, 0.f, 0.f};
    acc2[1] = (f32x4){0.f, 0.f, 0.f, 0.f};
    #pragma unroll
    for (int kk = 0; kk < 4; ++kk) {
        #pragma unroll
        for (int t = 0; t < 2; ++t) {
            int nt = wave * 2 + t;
            bf16x8 b = *(const bf16x8*)&WT[(size_t)(nt * 16 + l16) * 128 + kk * 32 + quad * 8];
            acc2[t] = __builtin_amdgcn_mfma_f32_16x16x32_bf16(a2[kk], b, acc2[t], 0, 0, 0);
        }
    }
    #pragma unroll
    for (int t = 0; t < 2; ++t) {
        int nt = wave * 2 + t;
        #pragma unroll
        for (int r = 0; r < 4; ++r) {
            int rr = base + quad * 4 + r;
            if (rr < N) acat[(size_t)rr * 128 + nt * 16 + l16] = f2b(acc2[t][r]);
        }
    }
}

// ---------------------------------------------------------------------------
// k_B tile body (round-6 k_B verbatim, parameterized by tile t).
// ---------------------------------------------------------------------------
__device__ void B_tile(
    unsigned short* sm, const KP& p, int t, int last,
    const unsigned short* __restrict__ acat, const unsigned short* __restrict__ xlin,
    const unsigned short* __restrict__ LWn, const unsigned short* __restrict__ WTn,
    const float* __restrict__ lbn,
    unsigned short* __restrict__ xlin_o, unsigned short* __restrict__ acat_o,
    const float* __restrict__ ae, const float* __restrict__ emb,
    const float* __restrict__ w2, const float* __restrict__ b2,
    const float* __restrict__ sib, const float* __restrict__ g,
    const float* __restrict__ b, const float* __restrict__ curv,
    const float* __restrict__ curv_n)
{
    int tid = threadIdx.x;
    int lane = tid & 63;
    int quad = lane >> 4;
    int l16  = lane & 15;
    int wv   = tid >> 6;
    int wid  = t * 16 + wv * 4 + quad;           // node id (one per quad)
    int N    = p.N;
    bool nv  = wid < N;
    int widc = nv ? wid : N - 1;

    __syncthreads();   // protect sm reuse across grid-stride tile iterations

    // long-latency independent loads first
    int dg = p.deg[widc];
    const int4* bp = (const int4*)(p.epack + (size_t)widc * KMAX);
    int4 myent = bp[l16];                        // bucket entries 2*l16, 2*l16+1
    float4 xt0 = *(const float4*)&p.xtf[(size_t)widc * 128 + 8 * l16];
    float4 xt1 = *(const float4*)&p.xtf[(size_t)widc * 128 + 8 * l16 + 4];
    ushort4 adu = *(const ushort4*)&acat[(size_t)widc * 128 + 4 * l16];
    float4 w2v = *(const float4*)&w2[4 * l16];

    float c = fminf(fmaxf(curv[0], 0.1f), 10.f);
    float sqc = fsqrt2(c);
    float rsqc = frcp(sqc);
    dg = dg < KMAX ? dg : KMAX;
    dg = nv ? dg : 0;

    float ad0 = b2f(adu.x), ad1 = b2f(adu.y), ad2 = b2f(adu.z), ad3 = b2f(adu.w);
    float b2v = b2[0], sibv = sib[0];

    float acc[8];
    #pragma unroll
    for (int j = 0; j < 8; ++j) acc[j] = 0.f;
    float S = 0.f;
    float4 St = make_float4(0.f, 0.f, 0.f, 0.f);   // per-edge-type coeff sums

    // wave-uniform pair-trip count (max over the 4 quads)
    int jm = dg;
    jm = max(jm, __shfl_xor(jm, 16, WAVE));
    jm = max(jm, __shfl_xor(jm, 32, WAVE));
    int jmax = (jm + 1) >> 1;

    // pair lookahead state (edges 2j, 2j+1 of this quad's node)
    ushort4 asuA_n, asuB_n; bf16x8 xuA_n, xuB_n; float4 avA_n, avB_n;
    float wA_n = 1.f, wB_n = 1.f; int tA_n = 0, tB_n = 0;
    bool eA_n = false, eB_n = false;

#define FETCHP(J) {                                                           \
        int lsrc = (quad << 4) + (J);                                         \
        int r0x = __shfl(myent.x, lsrc, WAVE);                                \
        int r0y = __shfl(myent.y, lsrc, WAVE);                                \
        int r1x = __shfl(myent.z, lsrc, WAVE);                                \
        int r1y = __shfl(myent.w, lsrc, WAVE);                                \
        eA_n = (2 * (J)) < dg;                                                \
        eB_n = (2 * (J) + 1) < dg;                                            \
        int sA = eA_n ? (r0x & 0xFFFFFF) : 0;                                 \
        int sB = eB_n ? (r1x & 0xFFFFFF) : 0;                                 \
        tA_n = eA_n ? (int)(((unsigned)r0x) >> 24) : 0;                       \
        tB_n = eB_n ? (int)(((unsigned)r1x) >> 24) : 0;                       \
        wA_n = eA_n ? __int_as_float(r0y) : 1.f;                              \
        wB_n = eB_n ? __int_as_float(r1y) : 1.f;                              \
        asuA_n = *(const ushort4*)&acat[(size_t)sA * 128 + 64 + 4 * l16];     \
        asuB_n = *(const ushort4*)&acat[(size_t)sB * 128 + 64 + 4 * l16];     \
        avA_n  = *(const float4*)&ae[tA_n * 64 + 4 * l16];                    \
        avB_n  = *(const float4*)&ae[tB_n * 64 + 4 * l16];                    \
        xuA_n  = *(const bf16x8*)&xlin[(size_t)sA * 128 + 8 * l16];           \
        xuB_n  = *(const bf16x8*)&xlin[(size_t)sB * 128 + 8 * l16];           \
    }

    if (jmax > 0) FETCHP(0);
    for (int j = 0; j < jmax; ++j) {
        ushort4 asuA = asuA_n, asuB = asuB_n;
        bf16x8 xuA = xuA_n, xuB = xuB_n;
        float4 avA = avA_n, avB = avB_n;
        float wA = wA_n, wB = wB_n;
        int tA = tA_n, tB = tB_n;
        bool eA = eA_n, eB = eB_n;
        if (j + 1 < jmax) FETCHP(j + 1);

        float dA = silu(ad0 + b2f(asuA.x) + avA.x) * w2v.x
                 + silu(ad1 + b2f(asuA.y) + avA.y) * w2v.y
                 + silu(ad2 + b2f(asuA.z) + avA.z) * w2v.z
                 + silu(ad3 + b2f(asuA.w) + avA.w) * w2v.w;
        float dB = silu(ad0 + b2f(asuB.x) + avB.x) * w2v.x
                 + silu(ad1 + b2f(asuB.y) + avB.y) * w2v.y
                 + silu(ad2 + b2f(asuB.z) + avB.z) * w2v.z
                 + silu(ad3 + b2f(asuB.w) + avB.w) * w2v.w;
        #pragma unroll
        for (int m = 1; m < 16; m <<= 1) {
            dA += __shfl_xor(dA, m, WAVE);
            dB += __shfl_xor(dB, m, WAVE);
        }
        float sA = dA + b2v + __logf(fmaxf(wA, 1e-6f));
        if (tA == 1) sA += sibv;
        float exA = eA ? __expf(sA) : 0.f;
        S += exA;
        float cfA = exA * wA;

        float sB2 = dB + b2v + __logf(fmaxf(wB, 1e-6f));
        if (tB == 1) sB2 += sibv;
        float exB = eB ? __expf(sB2) : 0.f;
        S += exB;
        float cfB = exB * wB;

        #pragma unroll
        for (int k = 0; k < 8; ++k)
            acc[k] += b2f((unsigned short)xuA[k]) * cfA;
        #pragma unroll
        for (int k = 0; k < 8; ++k)
            acc[k] += b2f((unsigned short)xuB[k]) * cfB;
        St.x += (tA == 0) ? cfA : 0.f;
        St.y += (tA == 1) ? cfA : 0.f;
        St.z += (tA == 2) ? cfA : 0.f;
        St.w += (tA == 3) ? cfA : 0.f;
        St.x += (tB == 0) ? cfB : 0.f;
        St.y += (tB == 1) ? cfB : 0.f;
        St.z += (tB == 2) ? cfB : 0.f;
        St.w += (tB == 3) ? cfB : 0.f;
    }
#undef FETCHP

    // add emb contribution: acc += sum_t St[t] * emb[t][dims]
    #pragma unroll
    for (int tt = 0; tt < 4; ++tt) {
        float stv = (tt == 0) ? St.x : (tt == 1) ? St.y : (tt == 2) ? St.z : St.w;
        float4 em0 = *(const float4*)&emb[tt * 128 + 8 * l16];
        float4 em1 = *(const float4*)&emb[tt * 128 + 8 * l16 + 4];
        acc[0] += em0.x * stv; acc[1] += em0.y * stv;
        acc[2] += em0.z * stv; acc[3] += em0.w * stv;
        acc[4] += em1.x * stv; acc[5] += em1.y * stv;
        acc[6] += em1.z * stv; acc[7] += em1.w * stv;
    }

    float inv = frcp(S + 1e-16f);
    float y[8];
    y[0] = xt0.x + acc[0] * inv;
    y[1] = xt0.y + acc[1] * inv;
    y[2] = xt0.z + acc[2] * inv;
    y[3] = xt0.w + acc[3] * inv;
    y[4] = xt1.x + acc[4] * inv;
    y[5] = xt1.y + acc[5] * inv;
    y[6] = xt1.z + acc[6] * inv;
    y[7] = xt1.w + acc[7] * inv;

    // LayerNorm (16-lane reduce covers all 128 dims)
    float sum = 0.f, sq = 0.f;
    #pragma unroll
    for (int j = 0; j < 8; ++j) { sum += y[j]; sq += y[j] * y[j]; }
    #pragma unroll
    for (int m = 1; m < 16; m <<= 1) {
        sum += __shfl_xor(sum, m, WAVE);
        sq  += __shfl_xor(sq, m, WAVE);
    }
    float mu = sum * (1.f / 128.f);
    float var = sq * (1.f / 128.f) - mu * mu;
    float invs = frsq(var + 1e-5f);
    float4 g0 = *(const float4*)&g[8 * l16];
    float4 g1 = *(const float4*)&g[8 * l16 + 4];
    float4 bb0 = *(const float4*)&b[8 * l16];
    float4 bb1 = *(const float4*)&b[8 * l16 + 4];
    y[0] = (y[0] - mu) * invs * g0.x + bb0.x;
    y[1] = (y[1] - mu) * invs * g0.y + bb0.y;
    y[2] = (y[2] - mu) * invs * g0.z + bb0.z;
    y[3] = (y[3] - mu) * invs * g0.w + bb0.w;
    y[4] = (y[4] - mu) * invs * g1.x + bb1.x;
    y[5] = (y[5] - mu) * invs * g1.y + bb1.y;
    y[6] = (y[6] - mu) * invs * g1.z + bb1.z;
    y[7] = (y[7] - mu) * invs * g1.w + bb1.w;

    // exp map
    float nrm2 = 0.f;
    #pragma unroll
    for (int j = 0; j < 8; ++j) nrm2 += y[j] * y[j];
    #pragma unroll
    for (int m = 1; m < 16; m <<= 1) nrm2 += __shfl_xor(nrm2, m, WAVE);
    float nrm = fmaxf(fsqrt2(nrm2), 1e-6f);
    float th = sqc * nrm;
    float e = __expf(th);
    float einv = frcp(e);
    float ch = 0.5f * (e + einv);
    float sh = 0.5f * (e - einv);
    float sc = sh * frcp(sqc * nrm);

    if (last) {
        if (nv) {
            float* o = p.out + (size_t)wid * 129;
            if (l16 == 0) o[0] = ch * rsqc;
            #pragma unroll
            for (int j = 0; j < 8; ++j) o[1 + 8 * l16 + j] = y[j] * sc;
        }
    } else {
        // analytic logmap with next layer's curvature
        float x0 = ch * rsqc;
        float c2 = fminf(fmaxf(curv_n[0], 0.1f), 10.f);
        float sqc2 = fsqrt2(c2);
        float x0c = fmaxf(sqc2 * x0, 1.f + 1e-7f);
        float dist = facosh(x0c) * frcp(sqc2);
        float nsp = fmaxf(sh * rsqc, 1e-6f);
        float sf = sc * dist * frcp(nsp);
        float tf[8];
        bf16x8 o8;
        #pragma unroll
        for (int j = 0; j < 8; ++j) {
            tf[j] = y[j] * sf;
            o8[j] = (short)f2b(tf[j]);
        }
        if (nv) {
            *(float4*)&p.xtf[(size_t)wid * 128 + 8 * l16]     = make_float4(tf[0], tf[1], tf[2], tf[3]);
            *(float4*)&p.xtf[(size_t)wid * 128 + 8 * l16 + 4] = make_float4(tf[4], tf[5], tf[6], tf[7]);
        }
        // stage next-layer tangent into LDS and run next layer's dual GEMM
        *(bf16x8*)&sm[(tid >> 4) * 136 + 8 * l16] = o8;
        dual_gemm_16(sm, LWn, WTn, lbn, xlin_o, acat_o, t * 16, N, tid);
    }
}

// ---------------------------------------------------------------------------
// ONE cooperative dispatch: P0 weightprep||degzero||logmap ; P1 hist||A0 ;
// P2 B(0)+A1-tail ; P3 B(1,last). grid.sync() between phases.
// ---------------------------------------------------------------------------
__global__ __launch_bounds__(256, 4) void k_all(KP p)
{
    __shared__ __align__(16) unsigned short sm[16 * 136];
    cg::grid_group grid = cg::this_grid();
    int nb = gridDim.x;
    int tid = threadIdx.x;

    // ---------------- P0 ----------------
    int tot0 = p.PB + p.ZB + p.NT;
    for (int w = blockIdx.x; w < tot0; w += nb) {
        if (w < p.PB) {
            int l = w / 129, bx = w % 129;
            const float* lwl = p.lin_w + (size_t)l * 16384;
            const float* w1l = p.w1 + (size_t)l * 384 * 64;
            if (bx < 64) {
                int idx = bx * 256 + tid;
                p.lw_bf[l * 16384 + idx] = f2b(lwl[idx]);
            } else if (bx < 128) {
                int idx = (bx - 64) * 256 + tid;
                int o = idx >> 7, i = idx & 127;
                float v = (o < 64) ? w1l[i * 64 + o] : w1l[(128 + i) * 64 + (o - 64)];
                p.Wt_bf[l * 16384 + idx] = f2b(v);
            } else {
                int t = tid >> 6, h = tid & 63;
                float s = p.b1[l * 64 + h];
                #pragma unroll 8
                for (int i = 0; i < 128; ++i)
                    s += p.emb[l * 512 + t * 128 + i] * w1l[(256 + i) * 64 + h];
                p.ae[l * 256 + tid] = s;
            }
        } else if (w < p.PB + p.ZB) {
            int i0 = ((w - p.PB) * 256 + tid) * 4;
            if (i0 + 3 < p.N) {
                *(int4*)&p.deg[i0] = make_int4(0, 0, 0, 0);
            } else {
                #pragma unroll
                for (int k2 = 0; k2 < 4; ++k2)
                    if (i0 + k2 < p.N) p.deg[i0 + k2] = 0;
            }
        } else {
            // logmap tile (layer-0 curvature): writes xtf (f32) + xtan_bf (bf16)
            int base = (w - p.PB - p.ZB) * 16;
            int l16  = tid & 15;
            int nloc = tid >> 4;
            int node = base + nloc;
            int nodec = node < p.N ? node : p.N - 1;

            float c = fminf(fmaxf(p.curv[0], 0.1f), 10.f);
            float sqc = fsqrt2(c);
            const float* row = p.x_hyp + (size_t)nodec * 129;
            float x0 = row[0];
            float v[8];
            #pragma unroll
            for (int j = 0; j < 8; ++j) v[j] = row[1 + 8 * l16 + j];
            float n2 = 0.f;
            #pragma unroll
            for (int j = 0; j < 8; ++j) n2 += v[j] * v[j];
            #pragma unroll
            for (int m = 1; m < 16; m <<= 1) n2 += __shfl_xor(n2, m, WAVE);
            float nrm = fmaxf(fsqrt2(n2), 1e-6f);
            float x0c = fmaxf(sqc * x0, 1.f + 1e-7f);
            float f = facosh(x0c) * frcp(sqc) * frcp(nrm);

            float vf[8];
            bf16x8 o8;
            #pragma unroll
            for (int j = 0; j < 8; ++j) {
                vf[j] = v[j] * f;
                o8[j] = (short)f2b(vf[j]);
            }
            if (node < p.N) {
                *(float4*)&p.xtf[(size_t)node * 128 + 8 * l16]     = make_float4(vf[0], vf[1], vf[2], vf[3]);
                *(float4*)&p.xtf[(size_t)node * 128 + 8 * l16 + 4] = make_float4(vf[4], vf[5], vf[6], vf[7]);
                *(bf16x8*)&p.xtan_bf[(size_t)node * 128 + 8 * l16] = o8;
            }
        }
    }
    grid.sync();

    // ---------------- P1 ----------------
    int tot1 = p.ECH + p.NT;
    for (int w = blockIdx.x; w < tot1; w += nb) {
        if (w < p.ECH) {
            int e = w * 256 + tid;
            if (e < p.E) {
                int dst = p.ei[p.E + e];
                int rank = atomicAdd(&p.deg[dst], 1);
                if (rank < KMAX) {
                    int2 r;
                    r.x = p.ei[e] | (p.et[e] << 24);
                    r.y = __float_as_int(p.ew[e]);
                    p.epack[(size_t)dst * KMAX + rank] = r;
                }
            }
        } else {
            // A0 tile: stage xtan_bf -> LDS, dual GEMM layer 0
            int t = w - p.ECH;
            int base = t * 16;
            int l16  = tid & 15;
            int nloc = tid >> 4;
            int node = base + nloc;
            int nodec = node < p.N ? node : p.N - 1;
            __syncthreads();   // protect sm reuse across grid-stride iterations
            *(bf16x8*)&sm[nloc * 136 + 8 * l16] =
                *(const bf16x8*)&p.xtan_bf[(size_t)nodec * 128 + 8 * l16];
            dual_gemm_16(sm, p.lw_bf, p.Wt_bf, p.lin_b, p.xlin0, p.acat0,
                         base, p.N, tid);
        }
    }
    grid.sync();

    // ---------------- P2.. : layers ----------------
    for (int l = 0; l < p.L; ++l) {
        int ln = (l + 1 < p.L) ? l + 1 : l;
        int last = (l == p.L - 1) ? 1 : 0;
        const unsigned short* xin = (l & 1) ? p.xlin1 : p.xlin0;
        const unsigned short* ain = (l & 1) ? p.acat1 : p.acat0;
        unsigned short* xot = (l & 1) ? p.xlin0 : p.xlin1;
        unsigned short* aot = (l & 1) ? p.acat0 : p.acat1;
        for (int t = blockIdx.x; t < p.NT; t += nb)
            B_tile(sm, p, t, last, ain, xin,
                   p.lw_bf + (size_t)ln * 16384, p.Wt_bf + (size_t)ln * 16384,
                   p.lin_b + (size_t)ln * 128, xot, aot,
                   p.ae + (size_t)l * 256, p.emb + (size_t)l * 512,
                   p.w2 + (size_t)l * 64, p.b2 + l, p.sib + l,
                   p.ln_g + (size_t)l * 128, p.ln_b + (size_t)l * 128,
                   p.curv + l, p.curv + ln);
        if (!last) grid.sync();
    }
}

// ---------------------------------------------------------------------------
extern "C" void kernel_launch(void* const* d_in, const int* in_sizes, int n_in,
                              void* d_out, int out_size, void* d_ws, size_t ws_size,
                              hipStream_t stream) {
    KP p;
    p.x_hyp = (const float*)d_in[0];
    p.ei    = (const int*)d_in[1];
    p.et    = (const int*)d_in[2];
    p.ew    = (const float*)d_in[3];
    p.lin_w = (const float*)d_in[4];
    p.lin_b = (const float*)d_in[5];
    p.ln_g  = (const float*)d_in[6];
    p.ln_b  = (const float*)d_in[7];
    p.emb   = (const float*)d_in[8];
    p.w1    = (const float*)d_in[9];
    p.b1    = (const float*)d_in[10];
    p.w2    = (const float*)d_in[11];
    p.b2    = (const float*)d_in[12];
    p.sib   = (const float*)d_in[13];
    p.curv  = (const float*)d_in[14];
    p.out   = (float*)d_out;

    p.N   = in_sizes[0] / 129;
    p.E   = in_sizes[2];
    p.L   = in_sizes[4] / (128 * 128);
    p.ECH = (p.E + 255) / 256;
    p.NT  = (p.N + 15) / 16;
    p.PB  = p.L * 129;
    p.ZB  = (p.N + 1023) / 1024;

    p.xtf = (float*)d_ws;                                          // N*128 f32
    p.xtan_bf = (unsigned short*)(p.xtf + (size_t)p.N * 128);      // N*128 bf16
    p.xlin0 = p.xtan_bf + (size_t)p.N * 128;                       // N*128 bf16
    p.acat0 = p.xlin0 + (size_t)p.N * 128;
    p.xlin1 = p.acat0 + (size_t)p.N * 128;
    p.acat1 = p.xlin1 + (size_t)p.N * 128;
    p.epack = (int2*)(p.acat1 + (size_t)p.N * 128);                // N*KMAX
    p.lw_bf = (unsigned short*)(p.epack + (size_t)p.N * KMAX);     // L*16384
    p.Wt_bf = p.lw_bf + (size_t)p.L * 16384;                       // L*16384
    p.ae    = (float*)(p.Wt_bf + (size_t)p.L * 16384);             // L*256
    p.deg   = (int*)(p.ae + (size_t)p.L * 256);                    // N

    static int gridBlocks = 0;
    if (gridBlocks == 0) {
        int perCU = 0;
        hipError_t err = hipOccupancyMaxActiveBlocksPerMultiprocessor(
            &perCU, k_all, 256, 0);
        int numCU = 256;
        hipDeviceProp_t prop;
        int dev = 0;
        if (hipGetDevice(&dev) == hipSuccess &&
            hipGetDeviceProperties(&prop, dev) == hipSuccess)
            numCU = prop.multiProcessorCount;
        if (err != hipSuccess || perCU < 1) perCU = 2;
        gridBlocks = perCU * numCU;
        if (gridBlocks < 256) gridBlocks = 256;
    }

    void* args[] = { (void*)&p };
    hipLaunchCooperativeKernel((void*)k_all, dim3(gridBlocks), dim3(256),
                               args, 0, stream);
}